// Round 4
// baseline (223.046 us; speedup 1.0000x reference)
//
#include <hip/hip_runtime.h>
#include <hip/hip_fp16.h>

typedef _Float16 f16;
typedef _Float16 f16x2 __attribute__((ext_vector_type(2)));
typedef _Float16 f16x4 __attribute__((ext_vector_type(4)));
typedef _Float16 f16x8 __attribute__((ext_vector_type(8)));
typedef float f32x4 __attribute__((ext_vector_type(4)));
typedef float f32x16 __attribute__((ext_vector_type(16)));

#define NHEADS 16
#define DHEAD 64
#define DM 1024
#define BATCH 4
#define SEQ 2048
#define MTOT (BATCH*SEQ)   // 8192

__device__ inline void gload_lds16(const void* g, void* l) {
  __builtin_amdgcn_global_load_lds(
      (const __attribute__((address_space(1))) void*)g,
      (__attribute__((address_space(3))) void*)l, 16, 0, 0);
}

__device__ inline float max3f(float a, float b, float c) {
  return fmaxf(fmaxf(a, b), c);   // fuses to v_max3_f32
}

__device__ inline unsigned pkrtz(float a, float b) {
  auto h = __builtin_amdgcn_cvt_pkrtz(a, b);   // v_cvt_pkrtz_f16_f32
  unsigned u; __builtin_memcpy(&u, &h, 4); return u;
}

// l += p.lo + p.hi with exact f32 accumulation of rounded-f16 P values
__device__ inline float accum2(unsigned w, float acc) {
  f16x2 p; __builtin_memcpy(&p, &w, 4);
#if __has_builtin(__builtin_amdgcn_fdot2)
  const f16x2 one2 = {(f16)1, (f16)1};
  return __builtin_amdgcn_fdot2(p, one2, acc, false);
#else
  return acc + (float)p[0] + (float)p[1];
#endif
}

__global__ __launch_bounds__(256) void cvt_f32_f16_k(const float* __restrict__ s,
                                                     f16* __restrict__ d, int n) {
  int i = (blockIdx.x * 256 + threadIdx.x) * 8;
  if (i + 8 <= n) {
    float4 a = *reinterpret_cast<const float4*>(s + i);
    float4 b = *reinterpret_cast<const float4*>(s + i + 4);
    f16x8 h = {(f16)a.x,(f16)a.y,(f16)a.z,(f16)a.w,(f16)b.x,(f16)b.y,(f16)b.z,(f16)b.w};
    *reinterpret_cast<f16x8*>(d + i) = h;
  } else {
    for (int j = i; j < n; ++j) d[j] = (f16)s[j];
  }
}

// 4 weight matrices (1M elems each) -> contiguous f16 at d (wq|wk|wv|wo)
__global__ __launch_bounds__(256) void cvt_w4_k(const float* __restrict__ w0,
                                                const float* __restrict__ w1,
                                                const float* __restrict__ w2,
                                                const float* __restrict__ w3,
                                                f16* __restrict__ d) {
  int which = blockIdx.x >> 9;                  // 512 blocks per W
  const float* s = which == 0 ? w0 : which == 1 ? w1 : which == 2 ? w2 : w3;
  int off = ((blockIdx.x & 511) * 256 + threadIdx.x) * 8;
  float4 a = *reinterpret_cast<const float4*>(s + off);
  float4 b = *reinterpret_cast<const float4*>(s + off + 4);
  f16x8 h = {(f16)a.x,(f16)a.y,(f16)a.z,(f16)a.w,(f16)b.x,(f16)b.y,(f16)b.z,(f16)b.w};
  *reinterpret_cast<f16x8*>(d + (size_t)which * DM * DM + off) = h;
}

// C[M][N] = A[M][K] * B[N][K]^T via 16x16x32 f16 MFMA; C scaled by oscale.
// Round-2 proven structure: 128x128 tile, BK=32, 4 waves, double-buffered LDS,
// stage(next) issued BEFORE ds_read+MFMA of cur, one barrier per K-step.
// ~4 blocks/CU of TLP does the latency hiding (m97-class structure).
// mode 0: f16 out, per-head [b*16+h][l][dh]   (Q, K)
// mode 1: f16 out, per-head [b*16+h][dh][l]   (V transposed)
// mode 2: f32 out, row-major [M][DM]          (final output)
template <int MODE>
__device__ void gemm_nt_body(const f16* __restrict__ A, const f16* __restrict__ Bw,
                             void* __restrict__ outp, int m0, int n0, float oscale,
                             f16* Ah, f16* Bh) {
  const int tx = threadIdx.x;
  const int wave = tx >> 6, lane = tx & 63;
  const int wm = (wave >> 1) * 64, wn = (wave & 1) * 64;

  f32x4 acc[4][4];
#pragma unroll
  for (int i = 0; i < 4; ++i)
#pragma unroll
    for (int j = 0; j < 4; ++j) acc[i][j] = {0.f, 0.f, 0.f, 0.f};

  const int srow = lane >> 2;
  const int scol = (lane & 3) * 8;

  auto stage = [&](int buf, int k0) {
#pragma unroll
    for (int i = 0; i < 2; ++i) {
      int chunk = wave * 2 + i;
      gload_lds16(A  + (size_t)(m0 + chunk * 16 + srow) * DM + k0 + scol,
                  Ah + buf * 4096 + chunk * 512);
      gload_lds16(Bw + (size_t)(n0 + chunk * 16 + srow) * DM + k0 + scol,
                  Bh + buf * 4096 + chunk * 512);
    }
  };

  stage(0, 0);
  __syncthreads();
  for (int k0 = 0; k0 < DM; k0 += 32) {
    const int cur = (k0 >> 5) & 1;
    if (k0 + 32 < DM) stage(cur ^ 1, k0 + 32);   // issue next BEFORE compute

    const f16* Ac = Ah + cur * 4096;
    const f16* Bc = Bh + cur * 4096;
    f16x8 af[4], bf[4];
#pragma unroll
    for (int i = 0; i < 4; ++i)
      af[i] = *reinterpret_cast<const f16x8*>(Ac + (wm + i * 16 + (lane & 15)) * 32 + (lane >> 4) * 8);
#pragma unroll
    for (int j = 0; j < 4; ++j)
      bf[j] = *reinterpret_cast<const f16x8*>(Bc + (wn + j * 16 + (lane & 15)) * 32 + (lane >> 4) * 8);
#pragma unroll
    for (int i = 0; i < 4; ++i)
#pragma unroll
      for (int j = 0; j < 4; ++j)
        acc[i][j] = __builtin_amdgcn_mfma_f32_16x16x32_f16(af[i], bf[j], acc[i][j], 0, 0, 0);
    __syncthreads();   // drains: cur reads done by all waves; next-stage landed
  }

  const int r0 = (lane >> 4) * 4, c0 = lane & 15;
#pragma unroll
  for (int i = 0; i < 4; ++i)
#pragma unroll
    for (int j = 0; j < 4; ++j)
#pragma unroll
      for (int r = 0; r < 4; ++r) {
        int gm = m0 + wm + i * 16 + r0 + r;
        int gn = n0 + wn + j * 16 + c0;
        float v = acc[i][j][r] * oscale;
        if (MODE == 2) {
          ((float*)outp)[(size_t)gm * DM + gn] = v;
        } else {
          int b = gm >> 11, l = gm & 2047, h = gn >> 6, d = gn & 63;
          size_t idx = (MODE == 0)
            ? (((size_t)(b * NHEADS + h) * SEQ + l) * DHEAD + d)
            : (((size_t)(b * NHEADS + h) * DHEAD + d) * SEQ + l);
          ((f16*)outp)[idx] = (f16)v;
        }
      }
}

// Fused QKV projection, T1 XCD-chunked swizzle: 1536 blocks -> each XCD gets
// 192 contiguous logical blocks = 8 consecutive m-panels (8 x 256KB = 2MB of x,
// fits the XCD's 4MB L2 and is reused by all 24 (which,n0) columns).
__global__ __launch_bounds__(256) void gemm_qkv(const f16* __restrict__ xh,
                                                const f16* __restrict__ Wf,  // wq|wk|wv
                                                f16* __restrict__ Qb,
                                                f16* __restrict__ Kb,
                                                f16* __restrict__ VTb,
                                                float qscale) {
  __shared__ f16 Ah[2 * 128 * 32];
  __shared__ f16 Bh[2 * 128 * 32];
  const int p = blockIdx.y * 24 + blockIdx.x;          // physical id (XCD = p%8)
  const int sw = (p & 7) * 192 + (p >> 3);             // bijective: 1536 = 8*192
  const int yy = sw / 24, xx = sw - yy * 24;
  const int which = xx >> 3;
  const int n0 = (xx & 7) * 128;
  const int m0 = yy * 128;
  const f16* Bw = Wf + (size_t)which * DM * DM;
  if (which == 0)      gemm_nt_body<0>(xh, Bw, Qb,  m0, n0, qscale, Ah, Bh);
  else if (which == 1) gemm_nt_body<0>(xh, Bw, Kb,  m0, n0, 1.0f,  Ah, Bh);
  else                 gemm_nt_body<1>(xh, Bw, VTb, m0, n0, 1.0f,  Ah, Bh);
}

// Output projection, T1 swizzle: 512 blocks -> each XCD gets 64 logical =
// 8 ctx-panels (2MB) + the whole Wo (2MB) = exactly its L2.
__global__ __launch_bounds__(256) void gemm_out(const f16* __restrict__ A,
                                                const f16* __restrict__ Bw,
                                                float* __restrict__ outp) {
  __shared__ f16 Ah[2 * 128 * 32];
  __shared__ f16 Bh[2 * 128 * 32];
  const int p = blockIdx.y * 8 + blockIdx.x;
  const int sw = (p & 7) * 64 + (p >> 3);              // bijective: 512 = 8*64
  const int yy = sw >> 3, xx = sw & 7;
  gemm_nt_body<2>(A, Bw, outp, yy * 128, xx * 128, 1.0f, Ah, Bh);
}

// Flash attention, swapped-operand, 32x32x16 MFMA, 2-phase double-buffered LDS.
// Block = (bh, 256 q); 8 waves x 32 q. Per 64-key tile, each 32-key kt-subtile
// is processed QK^T -> softmax -> pack -> PV. l is a scalar per lane via
// v_dot2_f32_f16. 8 waves share the same K/V staging. Grid 512 = 2 gens.
// XCD-chunked swizzle: each XCD gets 8 contiguous bh (K/V 4MB = its L2).
__global__ __launch_bounds__(512, 4) void attn_k(const f16* __restrict__ Q,
                                                 const f16* __restrict__ Kg,
                                                 const f16* __restrict__ VT,
                                                 f16* __restrict__ ctx) {
  __shared__ f16 Kt[2][64 * 64];    // [key][d], XOR-swizzled 8-f16 granules
  __shared__ f16 Vt[2][64 * 64];    // [d][key], same
  const int tx = threadIdx.x, wave = tx >> 6, lane = tx & 63;
  const int m = lane & 31, hi = lane >> 5, m7 = m & 7;

  // bijective XCD-chunk swizzle (512 blocks, 512 % 8 == 0):
  const int bid = blockIdx.y * 8 + blockIdx.x;
  const int swz = (bid & 7) * 64 + (bid >> 3);
  const int bh = swz >> 3;
  const int q0 = (swz & 7) * 256;

  const f16* Qb = Q  + (size_t)bh * SEQ * DHEAD;
  const f16* Kb = Kg + (size_t)bh * SEQ * DHEAD;
  const f16* Vb = VT + (size_t)bh * DHEAD * SEQ;

  // staging: 512 threads x 1 granule per tensor per buffer
  const int rs = tx >> 3;
  const int sc = ((tx & 7) ^ (rs & 7)) * 8;

  auto stage = [&](int buf, int k0) {
    gload_lds16(Kb + (size_t)(k0 + rs) * DHEAD + sc, &Kt[buf][(size_t)(wave * 64) * 8]);
    gload_lds16(Vb + (size_t)rs * SEQ + k0 + sc,     &Vt[buf][(size_t)(wave * 64) * 8]);
  };

  // Q B-operand fragments: q = q0 + wave*32 + m, d = s*16 + hi*8 + i
  f16x8 qb[4];
#pragma unroll
  for (int s = 0; s < 4; ++s)
    qb[s] = *reinterpret_cast<const f16x8*>(
        Qb + (size_t)(q0 + wave * 32 + m) * DHEAD + s * 16 + hi * 8);

  f32x16 oacc[2];
#pragma unroll
  for (int r = 0; r < 16; ++r) { oacc[0][r] = 0.f; oacc[1][r] = 0.f; }
  float lsum = 0.f;
  float mrun = -1e30f;

  auto compute = [&](const f16* Kc, const f16* Vc) {
#pragma unroll
    for (int kt = 0; kt < 2; ++kt) {
      // QK^T for this 32-key subtile: S^T[32 keys][32 q], chained over d
      f32x16 st;
#pragma unroll
      for (int r = 0; r < 16; ++r) st[r] = 0.f;
      __builtin_amdgcn_s_setprio(1);
#pragma unroll
      for (int s = 0; s < 4; ++s) {
        f16x8 ka = *reinterpret_cast<const f16x8*>(
            Kc + ((kt * 32 + m) * 8 + ((2 * s + hi) ^ m7)) * 8);
        st = __builtin_amdgcn_mfma_f32_32x32x16_f16(ka, qb[s], st, 0, 0, 0);
      }
      __builtin_amdgcn_s_setprio(0);

      // subtile max: lane-local 16 values + one cross-half shuffle
      float a0 = max3f(st[0], st[1], st[2]);
      float a1 = max3f(st[3], st[4], st[5]);
      float a2 = max3f(st[6], st[7], st[8]);
      float a3 = max3f(st[9], st[10], st[11]);
      float a4 = max3f(st[12], st[13], st[14]);
      float mx = fmaxf(fmaxf(max3f(a0, a1, a2), fmaxf(a3, a4)), st[15]);
      mx = fmaxf(mx, __shfl_xor(mx, 32));

      // defer-rescale: only pay when some row grew > 2^8
      if (!__all(mx <= mrun + 8.f)) {
        float mnew = fmaxf(mrun, mx);
        float scl = __builtin_amdgcn_exp2f(mrun - mnew);
#pragma unroll
        for (int r = 0; r < 16; ++r) { oacc[0][r] *= scl; oacc[1][r] *= scl; }
        lsum *= scl;
        mrun = mnew;
      }

      // P = exp2(S - mrun) (bounded 2^8), packed f16 pairs; l += sum(P) exact
      unsigned pk[8];
#pragma unroll
      for (int j = 0; j < 8; ++j)
        pk[j] = pkrtz(__builtin_amdgcn_exp2f(st[2 * j] - mrun),
                      __builtin_amdgcn_exp2f(st[2 * j + 1] - mrun));
#pragma unroll
      for (int j = 0; j < 8; ++j) lsum = accum2(pk[j], lsum);

      // PV: O^T[d][q] += V^T * P^T per 16-key chunk; B-frag in-register via
      // 2x v_permlane32_swap (fills two words each)
      __builtin_amdgcn_s_setprio(1);
#pragma unroll
      for (int c1 = 0; c1 < 2; ++c1) {
        const int c = kt * 2 + c1;
        unsigned w0 = pk[4 * c1 + 0], w1 = pk[4 * c1 + 1];
        unsigned w2 = pk[4 * c1 + 2], w3 = pk[4 * c1 + 3];
        asm("v_permlane32_swap_b32 %0, %1" : "+v"(w0), "+v"(w2));
        asm("v_permlane32_swap_b32 %0, %1" : "+v"(w1), "+v"(w3));
        union { unsigned u[4]; f16x8 h; } pu;
        pu.u[0] = w0; pu.u[1] = w1; pu.u[2] = w2; pu.u[3] = w3;
#pragma unroll
        for (int dt = 0; dt < 2; ++dt) {
          f16x8 va = *reinterpret_cast<const f16x8*>(
              Vc + ((dt * 32 + m) * 8 + ((2 * c + hi) ^ m7)) * 8);
          oacc[dt] = __builtin_amdgcn_mfma_f32_32x32x16_f16(va, pu.h, oacc[dt], 0, 0, 0);
        }
      }
      __builtin_amdgcn_s_setprio(0);
    }
  };

  // 2-phase pipeline: issue next tile's loads, compute current, one barrier/tile
  stage(0, 0);
  __syncthreads();
  for (int tt = 0; tt < 32; tt += 2) {
    stage(1, (tt + 1) * 64);
    compute(Kt[0], Vt[0]);
    __syncthreads();               // drains vmcnt: buf1 staged; buf0 reads done
    if (tt + 2 < 32) stage(0, (tt + 2) * 64);
    compute(Kt[1], Vt[1]);
    __syncthreads();
  }

  // epilogue: lane holds sum over its 32 keys/tile; partner has the other 32
  const float ltot = lsum + __shfl_xor(lsum, 32);
  const float inv = 1.0f / ltot;
  const int b = bh >> 4, hd = bh & 15;
  const int q = q0 + wave * 32 + m;
  f16* obase = ctx + ((size_t)b * SEQ + q) * DM + hd * DHEAD;
#pragma unroll
  for (int dt = 0; dt < 2; ++dt)
#pragma unroll
    for (int t = 0; t < 4; ++t) {
      f16x4 o = {(f16)(oacc[dt][4 * t + 0] * inv), (f16)(oacc[dt][4 * t + 1] * inv),
                 (f16)(oacc[dt][4 * t + 2] * inv), (f16)(oacc[dt][4 * t + 3] * inv)};
      *reinterpret_cast<f16x4*>(obase + dt * 32 + t * 8 + 4 * hi) = o;
    }
}

extern "C" void kernel_launch(void* const* d_in, const int* in_sizes, int n_in,
                              void* d_out, int out_size, void* d_ws, size_t ws_size,
                              hipStream_t stream) {
  (void)in_sizes; (void)n_in; (void)out_size; (void)ws_size;
  const float* x  = (const float*)d_in[0];
  const float* Wq = (const float*)d_in[1];
  const float* Wk = (const float*)d_in[2];
  const float* Wv = (const float*)d_in[3];
  const float* Wo = (const float*)d_in[4];

  char* ws = (char*)d_ws;
  const size_t SZ_X = (size_t)MTOT * DM * sizeof(f16);  // 16 MB
  const size_t SZ_W = (size_t)DM * DM * sizeof(f16);    // 2 MB
  f16* xh  = (f16*)(ws);
  f16* wfh = (f16*)(ws + SZ_X);                          // wq|wk|wv|wo contiguous
  f16* woh = (f16*)(ws + SZ_X + 3 * SZ_W);
  f16* Qb  = (f16*)(ws + 1 * SZ_X + 4 * SZ_W);
  f16* Kb  = (f16*)(ws + 2 * SZ_X + 4 * SZ_W);
  f16* VTb = (f16*)(ws + 3 * SZ_X + 4 * SZ_W);
  f16* ctx = xh;  // x_f16 dead after QKV projections; reuse as ctx

  const int nx = MTOT * DM;
  const float QSCALE = 0.125f * 1.44269504088896f;  // 1/sqrt(64) * log2(e)

  cvt_f32_f16_k<<<nx / 2048, 256, 0, stream>>>(x, xh, nx);
  cvt_w4_k<<<2048, 256, 0, stream>>>(Wq, Wk, Wv, Wo, wfh);

  gemm_qkv<<<dim3(24, MTOT / 128), 256, 0, stream>>>(xh, wfh, Qb, Kb, VTb, QSCALE);

  attn_k<<<dim3(SEQ / 256, BATCH * NHEADS), 512, 0, stream>>>(Qb, Kb, VTb, ctx);

  gemm_out<<<dim3(DM / 128, MTOT / 128), 256, 0, stream>>>(ctx, woh, (float*)d_out);
}

// Round 5
// 198.190 us; speedup vs baseline: 1.1254x; 1.1254x over previous
//
#include <hip/hip_runtime.h>
#include <hip/hip_fp16.h>

typedef _Float16 f16;
typedef _Float16 f16x2 __attribute__((ext_vector_type(2)));
typedef _Float16 f16x4 __attribute__((ext_vector_type(4)));
typedef _Float16 f16x8 __attribute__((ext_vector_type(8)));
typedef float f32x4 __attribute__((ext_vector_type(4)));
typedef float f32x16 __attribute__((ext_vector_type(16)));

#define NHEADS 16
#define DHEAD 64
#define DM 1024
#define BATCH 4
#define SEQ 2048
#define MTOT (BATCH*SEQ)   // 8192

__device__ inline void gload_lds16(const void* g, void* l) {
  __builtin_amdgcn_global_load_lds(
      (const __attribute__((address_space(1))) void*)g,
      (__attribute__((address_space(3))) void*)l, 16, 0, 0);
}

__device__ inline float max3f(float a, float b, float c) {
  return fmaxf(fmaxf(a, b), c);   // fuses to v_max3_f32
}

__device__ inline unsigned pkrtz(float a, float b) {
  auto h = __builtin_amdgcn_cvt_pkrtz(a, b);   // v_cvt_pkrtz_f16_f32
  unsigned u; __builtin_memcpy(&u, &h, 4); return u;
}

// l += p.lo + p.hi with exact f32 accumulation of rounded-f16 P values
__device__ inline float accum2(unsigned w, float acc) {
  f16x2 p; __builtin_memcpy(&p, &w, 4);
#if __has_builtin(__builtin_amdgcn_fdot2)
  const f16x2 one2 = {(f16)1, (f16)1};
  return __builtin_amdgcn_fdot2(p, one2, acc, false);
#else
  return acc + (float)p[0] + (float)p[1];
#endif
}

__global__ __launch_bounds__(256) void cvt_f32_f16_k(const float* __restrict__ s,
                                                     f16* __restrict__ d, int n) {
  int i = (blockIdx.x * 256 + threadIdx.x) * 8;
  if (i + 8 <= n) {
    float4 a = *reinterpret_cast<const float4*>(s + i);
    float4 b = *reinterpret_cast<const float4*>(s + i + 4);
    f16x8 h = {(f16)a.x,(f16)a.y,(f16)a.z,(f16)a.w,(f16)b.x,(f16)b.y,(f16)b.z,(f16)b.w};
    *reinterpret_cast<f16x8*>(d + i) = h;
  } else {
    for (int j = i; j < n; ++j) d[j] = (f16)s[j];
  }
}

// 4 weight matrices (1M elems each) -> contiguous f16 at d (wq|wk|wv|wo)
__global__ __launch_bounds__(256) void cvt_w4_k(const float* __restrict__ w0,
                                                const float* __restrict__ w1,
                                                const float* __restrict__ w2,
                                                const float* __restrict__ w3,
                                                f16* __restrict__ d) {
  int which = blockIdx.x >> 9;                  // 512 blocks per W
  const float* s = which == 0 ? w0 : which == 1 ? w1 : which == 2 ? w2 : w3;
  int off = ((blockIdx.x & 511) * 256 + threadIdx.x) * 8;
  float4 a = *reinterpret_cast<const float4*>(s + off);
  float4 b = *reinterpret_cast<const float4*>(s + off + 4);
  f16x8 h = {(f16)a.x,(f16)a.y,(f16)a.z,(f16)a.w,(f16)b.x,(f16)b.y,(f16)b.z,(f16)b.w};
  *reinterpret_cast<f16x8*>(d + (size_t)which * DM * DM + off) = h;
}

// C[M][N] = A[M][K] * B[N][K]^T via 16x16x32 f16 MFMA; C scaled by oscale.
// Round-2 proven structure EXACTLY: 128x128 tile, BK=32, 4 waves, double-buffered
// LDS, stage(next) issued BEFORE ds_read+MFMA of cur, one barrier per K-step.
// Default block->XCD round-robin keeps each XCD on 3 fixed weight columns
// (768 KB L2-resident) -- do NOT swizzle (round-4 regression).
// mode 0: f16 out, per-head [b*16+h][l][dh]   (Q, K)
// mode 1: f16 out, per-head [b*16+h][dh][l]   (V transposed)
// mode 2: f32 out, row-major [M][DM]          (final output)
template <int MODE>
__device__ void gemm_nt_body(const f16* __restrict__ A, const f16* __restrict__ Bw,
                             void* __restrict__ outp, int n0, float oscale,
                             f16* Ah, f16* Bh) {
  const int tx = threadIdx.x;
  const int wave = tx >> 6, lane = tx & 63;
  const int m0 = blockIdx.y * 128;
  const int wm = (wave >> 1) * 64, wn = (wave & 1) * 64;

  f32x4 acc[4][4];
#pragma unroll
  for (int i = 0; i < 4; ++i)
#pragma unroll
    for (int j = 0; j < 4; ++j) acc[i][j] = {0.f, 0.f, 0.f, 0.f};

  const int srow = lane >> 2;
  const int scol = (lane & 3) * 8;

  auto stage = [&](int buf, int k0) {
#pragma unroll
    for (int i = 0; i < 2; ++i) {
      int chunk = wave * 2 + i;
      gload_lds16(A  + (size_t)(m0 + chunk * 16 + srow) * DM + k0 + scol,
                  Ah + buf * 4096 + chunk * 512);
      gload_lds16(Bw + (size_t)(n0 + chunk * 16 + srow) * DM + k0 + scol,
                  Bh + buf * 4096 + chunk * 512);
    }
  };

  stage(0, 0);
  __syncthreads();
  for (int k0 = 0; k0 < DM; k0 += 32) {
    const int cur = (k0 >> 5) & 1;
    if (k0 + 32 < DM) stage(cur ^ 1, k0 + 32);   // issue next BEFORE compute

    const f16* Ac = Ah + cur * 4096;
    const f16* Bc = Bh + cur * 4096;
    f16x8 af[4], bf[4];
#pragma unroll
    for (int i = 0; i < 4; ++i)
      af[i] = *reinterpret_cast<const f16x8*>(Ac + (wm + i * 16 + (lane & 15)) * 32 + (lane >> 4) * 8);
#pragma unroll
    for (int j = 0; j < 4; ++j)
      bf[j] = *reinterpret_cast<const f16x8*>(Bc + (wn + j * 16 + (lane & 15)) * 32 + (lane >> 4) * 8);
#pragma unroll
    for (int i = 0; i < 4; ++i)
#pragma unroll
      for (int j = 0; j < 4; ++j)
        acc[i][j] = __builtin_amdgcn_mfma_f32_16x16x32_f16(af[i], bf[j], acc[i][j], 0, 0, 0);
    __syncthreads();   // drains: cur reads done by all waves; next-stage landed
  }

  const int r0 = (lane >> 4) * 4, c0 = lane & 15;
#pragma unroll
  for (int i = 0; i < 4; ++i)
#pragma unroll
    for (int j = 0; j < 4; ++j)
#pragma unroll
      for (int r = 0; r < 4; ++r) {
        int gm = m0 + wm + i * 16 + r0 + r;
        int gn = n0 + wn + j * 16 + c0;
        float v = acc[i][j][r] * oscale;
        if (MODE == 2) {
          ((float*)outp)[(size_t)gm * DM + gn] = v;
        } else {
          int b = gm >> 11, l = gm & 2047, h = gn >> 6, d = gn & 63;
          size_t idx = (MODE == 0)
            ? (((size_t)(b * NHEADS + h) * SEQ + l) * DHEAD + d)
            : (((size_t)(b * NHEADS + h) * DHEAD + d) * SEQ + l);
          ((f16*)outp)[idx] = (f16)v;
        }
      }
}

// Fused QKV projection: blockIdx.x 0-7 -> Q, 8-15 -> K, 16-23 -> V^T
__global__ __launch_bounds__(256) void gemm_qkv(const f16* __restrict__ xh,
                                                const f16* __restrict__ Wf,  // wq|wk|wv
                                                f16* __restrict__ Qb,
                                                f16* __restrict__ Kb,
                                                f16* __restrict__ VTb,
                                                float qscale) {
  __shared__ f16 Ah[2 * 128 * 32];
  __shared__ f16 Bh[2 * 128 * 32];
  int which = blockIdx.x >> 3;
  int n0 = (blockIdx.x & 7) * 128;
  const f16* Bw = Wf + (size_t)which * DM * DM;
  if (which == 0)      gemm_nt_body<0>(xh, Bw, Qb,  n0, qscale, Ah, Bh);
  else if (which == 1) gemm_nt_body<0>(xh, Bw, Kb,  n0, 1.0f,  Ah, Bh);
  else                 gemm_nt_body<1>(xh, Bw, VTb, n0, 1.0f,  Ah, Bh);
}

__global__ __launch_bounds__(256) void gemm_out(const f16* __restrict__ A,
                                                const f16* __restrict__ Bw,
                                                float* __restrict__ outp) {
  __shared__ f16 Ah[2 * 128 * 32];
  __shared__ f16 Bh[2 * 128 * 32];
  gemm_nt_body<2>(A, Bw, outp, blockIdx.x * 128, 1.0f, Ah, Bh);
}

// Flash attention, swapped-operand, 32x32x16 MFMA, 2-phase double-buffered LDS.
// Block = (bh, 256 q); 8 waves x 32 q. KVBLK=128: halves the barrier/vmcnt-drain
// count vs 64 (the 2-phase stall source, m233) at identical per-element compute.
// K tile [128 key][64 d] (8 granules/row), V tile [64 d][128 key] (16/row),
// both XOR-swizzled kc' = kc ^ (row&7) on write AND read. l is a scalar per
// lane via v_dot2_f32_f16. Grid 512 = 2 blocks/CU (grid-capped; 64KB LDS ok).
// XCD-chunked swizzle kept: each XCD gets 8 contiguous bh (K/V 4MB = its L2).
__global__ __launch_bounds__(512, 4) void attn_k(const f16* __restrict__ Q,
                                                 const f16* __restrict__ Kg,
                                                 const f16* __restrict__ VT,
                                                 f16* __restrict__ ctx) {
  __shared__ f16 Kt[2][128 * 64];   // [key][d], XOR-swizzled 8-f16 granules
  __shared__ f16 Vt[2][64 * 128];   // [d][key], XOR-swizzled within 16-granule rows
  const int tx = threadIdx.x, wave = tx >> 6, lane = tx & 63;
  const int m = lane & 31, hi = lane >> 5, m7 = m & 7;

  // bijective XCD-chunk swizzle (512 blocks, 512 % 8 == 0):
  const int bid = blockIdx.y * 8 + blockIdx.x;
  const int swz = (bid & 7) * 64 + (bid >> 3);
  const int bh = swz >> 3;
  const int q0 = (swz & 7) * 256;

  const f16* Qb = Q  + (size_t)bh * SEQ * DHEAD;
  const f16* Kb = Kg + (size_t)bh * SEQ * DHEAD;
  const f16* Vb = VT + (size_t)bh * DHEAD * SEQ;

  // K staging: 1024 granules (128 rows x 8); thread t -> granules t, t+512
  const int rk = tx >> 3;                       // key row 0..63 (+64 for 2nd)
  const int sk = ((tx & 7) ^ (rk & 7)) * 8;     // swizzled d-col (same for row+64)
  // V staging: 1024 granules (64 rows x 16); thread t -> granules t, t+512
  const int rv = tx >> 4;                       // d row 0..31 (+32 for 2nd)
  const int sv = ((tx & 15) ^ (rv & 7)) * 8;    // swizzled key-col (same for row+32)

  auto stage = [&](int buf, int k0) {
    gload_lds16(Kb + (size_t)(k0 + rk) * DHEAD + sk,      &Kt[buf][(size_t)(wave * 64) * 8]);
    gload_lds16(Kb + (size_t)(k0 + 64 + rk) * DHEAD + sk, &Kt[buf][(size_t)(512 + wave * 64) * 8]);
    gload_lds16(Vb + (size_t)rv * SEQ + k0 + sv,          &Vt[buf][(size_t)(wave * 64) * 8]);
    gload_lds16(Vb + (size_t)(32 + rv) * SEQ + k0 + sv,   &Vt[buf][(size_t)(512 + wave * 64) * 8]);
  };

  // Q B-operand fragments: q = q0 + wave*32 + m, d = s*16 + hi*8 + i
  f16x8 qb[4];
#pragma unroll
  for (int s = 0; s < 4; ++s)
    qb[s] = *reinterpret_cast<const f16x8*>(
        Qb + (size_t)(q0 + wave * 32 + m) * DHEAD + s * 16 + hi * 8);

  f32x16 oacc[2];
#pragma unroll
  for (int r = 0; r < 16; ++r) { oacc[0][r] = 0.f; oacc[1][r] = 0.f; }
  float lsum = 0.f;
  float mrun = -1e30f;

  auto compute = [&](const f16* Kc, const f16* Vc) {
#pragma unroll
    for (int kt = 0; kt < 4; ++kt) {
      // QK^T for this 32-key subtile: S^T[32 keys][32 q], chained over d
      f32x16 st;
#pragma unroll
      for (int r = 0; r < 16; ++r) st[r] = 0.f;
      __builtin_amdgcn_s_setprio(1);
#pragma unroll
      for (int s = 0; s < 4; ++s) {
        f16x8 ka = *reinterpret_cast<const f16x8*>(
            Kc + ((kt * 32 + m) * 8 + ((2 * s + hi) ^ m7)) * 8);
        st = __builtin_amdgcn_mfma_f32_32x32x16_f16(ka, qb[s], st, 0, 0, 0);
      }
      __builtin_amdgcn_s_setprio(0);

      // subtile max: lane-local 16 values + one cross-half shuffle
      float a0 = max3f(st[0], st[1], st[2]);
      float a1 = max3f(st[3], st[4], st[5]);
      float a2 = max3f(st[6], st[7], st[8]);
      float a3 = max3f(st[9], st[10], st[11]);
      float a4 = max3f(st[12], st[13], st[14]);
      float mx = fmaxf(fmaxf(max3f(a0, a1, a2), fmaxf(a3, a4)), st[15]);
      mx = fmaxf(mx, __shfl_xor(mx, 32));

      // defer-rescale: only pay when some row grew > 2^8
      if (!__all(mx <= mrun + 8.f)) {
        float mnew = fmaxf(mrun, mx);
        float scl = __builtin_amdgcn_exp2f(mrun - mnew);
#pragma unroll
        for (int r = 0; r < 16; ++r) { oacc[0][r] *= scl; oacc[1][r] *= scl; }
        lsum *= scl;
        mrun = mnew;
      }

      // P = exp2(S - mrun) (bounded 2^8), packed f16 pairs; l += sum(P) exact
      unsigned pk[8];
#pragma unroll
      for (int j = 0; j < 8; ++j)
        pk[j] = pkrtz(__builtin_amdgcn_exp2f(st[2 * j] - mrun),
                      __builtin_amdgcn_exp2f(st[2 * j + 1] - mrun));
#pragma unroll
      for (int j = 0; j < 8; ++j) lsum = accum2(pk[j], lsum);

      // PV: O^T[d][q] += V^T * P^T per 16-key chunk; B-frag in-register via
      // 2x v_permlane32_swap (fills two words each)
      __builtin_amdgcn_s_setprio(1);
#pragma unroll
      for (int c1 = 0; c1 < 2; ++c1) {
        const int c = kt * 2 + c1;                 // global 16-key chunk 0..7
        unsigned w0 = pk[4 * c1 + 0], w1 = pk[4 * c1 + 1];
        unsigned w2 = pk[4 * c1 + 2], w3 = pk[4 * c1 + 3];
        asm("v_permlane32_swap_b32 %0, %1" : "+v"(w0), "+v"(w2));
        asm("v_permlane32_swap_b32 %0, %1" : "+v"(w1), "+v"(w3));
        union { unsigned u[4]; f16x8 h; } pu;
        pu.u[0] = w0; pu.u[1] = w1; pu.u[2] = w2; pu.u[3] = w3;
#pragma unroll
        for (int dt = 0; dt < 2; ++dt) {
          f16x8 va = *reinterpret_cast<const f16x8*>(
              Vc + ((dt * 32 + m) * 16 + ((2 * c + hi) ^ m7)) * 8);
          oacc[dt] = __builtin_amdgcn_mfma_f32_32x32x16_f16(va, pu.h, oacc[dt], 0, 0, 0);
        }
      }
      __builtin_amdgcn_s_setprio(0);
    }
  };

  // 2-phase pipeline over 16 x 128-key tiles: one barrier per tile
  stage(0, 0);
  __syncthreads();
  for (int tt = 0; tt < 16; tt += 2) {
    stage(1, (tt + 1) * 128);
    compute(Kt[0], Vt[0]);
    __syncthreads();               // drains vmcnt: buf1 staged; buf0 reads done
    if (tt + 2 < 16) stage(0, (tt + 2) * 128);
    compute(Kt[1], Vt[1]);
    __syncthreads();
  }

  // epilogue: lane holds sum over its half of the keys; partner has the rest
  const float ltot = lsum + __shfl_xor(lsum, 32);
  const float inv = 1.0f / ltot;
  const int b = bh >> 4, hd = bh & 15;
  const int q = q0 + wave * 32 + m;
  f16* obase = ctx + ((size_t)b * SEQ + q) * DM + hd * DHEAD;
#pragma unroll
  for (int dt = 0; dt < 2; ++dt)
#pragma unroll
    for (int t = 0; t < 4; ++t) {
      f16x4 o = {(f16)(oacc[dt][4 * t + 0] * inv), (f16)(oacc[dt][4 * t + 1] * inv),
                 (f16)(oacc[dt][4 * t + 2] * inv), (f16)(oacc[dt][4 * t + 3] * inv)};
      *reinterpret_cast<f16x4*>(obase + dt * 32 + t * 8 + 4 * hi) = o;
    }
}

extern "C" void kernel_launch(void* const* d_in, const int* in_sizes, int n_in,
                              void* d_out, int out_size, void* d_ws, size_t ws_size,
                              hipStream_t stream) {
  (void)in_sizes; (void)n_in; (void)out_size; (void)ws_size;
  const float* x  = (const float*)d_in[0];
  const float* Wq = (const float*)d_in[1];
  const float* Wk = (const float*)d_in[2];
  const float* Wv = (const float*)d_in[3];
  const float* Wo = (const float*)d_in[4];

  char* ws = (char*)d_ws;
  const size_t SZ_X = (size_t)MTOT * DM * sizeof(f16);  // 16 MB
  const size_t SZ_W = (size_t)DM * DM * sizeof(f16);    // 2 MB
  f16* xh  = (f16*)(ws);
  f16* wfh = (f16*)(ws + SZ_X);                          // wq|wk|wv|wo contiguous
  f16* woh = (f16*)(ws + SZ_X + 3 * SZ_W);
  f16* Qb  = (f16*)(ws + 1 * SZ_X + 4 * SZ_W);
  f16* Kb  = (f16*)(ws + 2 * SZ_X + 4 * SZ_W);
  f16* VTb = (f16*)(ws + 3 * SZ_X + 4 * SZ_W);
  f16* ctx = xh;  // x_f16 dead after QKV projections; reuse as ctx

  const int nx = MTOT * DM;
  const float QSCALE = 0.125f * 1.44269504088896f;  // 1/sqrt(64) * log2(e)

  cvt_f32_f16_k<<<nx / 2048, 256, 0, stream>>>(x, xh, nx);
  cvt_w4_k<<<2048, 256, 0, stream>>>(Wq, Wk, Wv, Wo, wfh);

  gemm_qkv<<<dim3(24, MTOT / 128), 256, 0, stream>>>(xh, wfh, Qb, Kb, VTb, QSCALE);

  attn_k<<<dim3(SEQ / 256, BATCH * NHEADS), 512, 0, stream>>>(Qb, Kb, VTb, ctx);

  gemm_out<<<dim3(DM / 128, MTOT / 128), 256, 0, stream>>>(ctx, woh, (float*)d_out);
}